// Round 15
// baseline (1514.903 us; speedup 1.0000x reference)
//
#include <hip/hip_runtime.h>

typedef unsigned short u16;
typedef short s16x8 __attribute__((ext_vector_type(8)));   // 8 bf16 bit-patterns
typedef float f32x4 __attribute__((ext_vector_type(4)));

#define DI __device__ __forceinline__

constexpr int N_ = 50000;
constexpr int E_ = 400000;
constexpr int G_ = 64;

DI u16 f2bf(float f) {
    union { unsigned u; float f; } c; c.f = f;
    unsigned u = c.u;
    u += 0x7fffu + ((u >> 16) & 1u);   // RNE
    return (u16)(u >> 16);
}

DI s16x8 ldv(const u16* p) { return *(const s16x8*)p; }
DI f32x4 MFMA(s16x8 a, s16x8 b, f32x4 c) {
    return __builtin_amdgcn_mfma_f32_16x16x32_bf16(a, b, c, 0, 0, 0);
}

// ---------------------------------------------------------------------------
// Named kernel: zero agg0+agg1 (40 MB) and repack weights f32 -> bf16 in
// MFMA-fragment-order tiles (lane-order sections, R14: conflict-free),
// folding [xi, xj-xi]@W = xi@(Wa-Wb) + xj@Wb.
// Section = 512 elems = 1 KB; element (col,kq,j) at lane*8+j, lane=kq*16+col.
// W1/W2 sec id = n0c*(2*KA)+s*2+b01 ; W3 sec id = ch*7+u.
// ---------------------------------------------------------------------------
__global__ __launch_bounds__(256)
void ModelGNN_35304631174019_kernel(
          const float* __restrict__ l0w1, const float* __restrict__ l0w2,
          const float* __restrict__ l0w3, const float* __restrict__ l1w1,
          const float* __restrict__ l1w2, const float* __restrict__ l1w3,
          float4* __restrict__ aggz,
          u16* __restrict__ wt0, u16* __restrict__ wt1,
          u16* __restrict__ wt2a, u16* __restrict__ wt2b,
          u16* __restrict__ wt3a, u16* __restrict__ wt3b)
{
    int i = blockIdx.x * 256 + threadIdx.x;
    if (i < 2500000) { aggz[i] = make_float4(0.f, 0.f, 0.f, 0.f); return; }  // agg0+agg1
    int f = i - 2500000;

    if (f < 10240) {                       // wt0: layer0 W1, KP=32 (KA=1)
        int sec = f >> 9, w = f & 511;
        int lane = w >> 3, j = w & 7;
        int col = lane & 15, kq = lane >> 4;
        int n0c = sec >> 1, b01 = sec & 1;
        int n = n0c * 32 + b01 * 16 + col, k = kq * 8 + j;
        u16 v = 0;
        if (n < 300) {
            if (k < 7) v = f2bf(l0w1[k * 300 + n] - l0w1[(7 + k) * 300 + n]);
            else if (k >= 16 && k < 23) v = f2bf(l0w1[(7 + (k - 16)) * 300 + n]);
        }
        wt0[f] = v; return;
    }
    f -= 10240;
    if (f < 71680) {                       // wt1: layer1 W1, KP=224 (KA=7)
        int sec = f >> 9, w = f & 511;
        int lane = w >> 3, j = w & 7;
        int col = lane & 15, kq = lane >> 4;
        int n0c = sec / 14, r = sec % 14;
        int s = r >> 1, b01 = r & 1;
        int n = n0c * 32 + b01 * 16 + col, k = s * 32 + kq * 8 + j;
        u16 v = 0;
        if (n < 300) {
            if (k < 100) v = f2bf(l1w1[k * 300 + n] - l1w1[(100 + k) * 300 + n]);
            else if (k >= 112 && k < 212) v = f2bf(l1w1[(100 + (k - 112)) * 300 + n]);
        }
        wt1[f] = v; return;
    }
    f -= 71680;
    if (f < 204800) {                      // wt2a / wt2b: 300x300, K=320 (KA=10)
        const float* src = (f < 102400) ? l0w2 : l1w2;
        u16* dst = (f < 102400) ? wt2a : wt2b;
        int f2 = (f < 102400) ? f : f - 102400;
        int sec = f2 >> 9, w = f2 & 511;
        int lane = w >> 3, j = w & 7;
        int col = lane & 15, kq = lane >> 4;
        int n0c = sec / 20, r = sec % 20;
        int s = r >> 1, b01 = r & 1;
        int n = n0c * 32 + b01 * 16 + col, k = s * 32 + kq * 8 + j;
        dst[f2] = (n < 300 && k < 300) ? f2bf(src[k * 300 + n]) : (u16)0;
        return;
    }
    f -= 204800;
    if (f < 71680) {                       // wt3a / wt3b: 300x100 -> [112 n3][320 k]
        const float* src = (f < 35840) ? l0w3 : l1w3;
        u16* dst = (f < 35840) ? wt3a : wt3b;
        int f2 = (f < 35840) ? f : f - 35840;
        int sec = f2 >> 9, w = f2 & 511;
        int lane = w >> 3, j = w & 7;
        int col = lane & 15, kq = lane >> 4;
        int ch = sec / 7, u = sec % 7;
        int n3 = u * 16 + col, k = ch * 32 + kq * 8 + j;
        dst[f2] = (n3 < 100 && k < 300) ? f2bf(src[k * 100 + n3]) : (u16)0;
        return;
    }
}

// ---------------------------------------------------------------------------
// convert: agg0 f32[50000][100] -> agg0bf bf16[50000][104] (4 zero pad cols).
// Same RNE rounding point as before -> bit-identical math downstream.
// ---------------------------------------------------------------------------
__global__ __launch_bounds__(256)
void convert_bf(const float* __restrict__ agg0, u16* __restrict__ out)
{
    int i = blockIdx.x * 256 + threadIdx.x;
    if (i >= N_ * 104) return;
    int n = i / 104, c = i - n * 104;
    out[i] = (c < 100) ? f2bf(agg0[n * 100 + c]) : (u16)0;
}

// ---------------------------------------------------------------------------
// edge_mlp: fused per-edge 3-layer MLP + clamped scatter-max via MFMA.
// R15 geometry: 512-thread blocks (8 waves) x 32 edges/wave (two 16-row
// A-tiles) = 256 edges/block -> 1563 blocks. Staging bytes/edge drop 4x vs
// R14 (layer-0/1 staging stream 1.86/2.6 GB -> 0.46/0.66 GB); each staged
// fragment feeds 4 MFMA. R14 evidence: dur == hbm_bytes/2.6TB/s, FETCH
// dominated by staging misses (layer-0 has no gather yet same 1.18 GB).
// WBUF lane-order sections: conflict-free ds_read_b128 (R14, 43M->2M).
// Layouts (m89/m120): A: m=lane&15,k=quad*8+j ; B: n=lane&15,k=quad*8+j ;
// C/D: col=lane&15, row=quad*4+reg.
// relu(where(cnt>0,segmax,0)) == int atomicMax of relu'd msgs into 0-init buf;
// max_r(relu(m_r+b)) == relu(max_r(m_r)+b) (relu monotone, b uniform).
// ---------------------------------------------------------------------------
template<bool FIRST>
__global__ __launch_bounds__(512, 2)
void edge_mlp(const float* __restrict__ X, const u16* __restrict__ H0,
              const int* __restrict__ ei,
              const u16* __restrict__ W1, const float* __restrict__ B1,
              const u16* __restrict__ W2, const float* __restrict__ B2,
              const u16* __restrict__ W3, const float* __restrict__ B3,
              float* __restrict__ agg)
{
    constexpr int KP = FIRST ? 32 : 224;
    constexpr int KA = KP / 32;                       // 1 or 7
    __shared__ __align__(16) u16 WBUF[27 * 512];      // 27,648 B block-shared
    __shared__ __align__(16) u16 SCR[8 * 32 * 40];    // 20,480 B wave-private slices

    const int tid  = threadIdx.x;
    const int wave = tid >> 6, lane = tid & 63;
    const int col  = lane & 15, kq = lane >> 4;
    const int ebase = blockIdx.x * 256 + wave * 32;   // 32 edges per wave
    const int fragoff = lane * 8;                     // lane-order: conflict-free
    u16* SCw = SCR + wave * (32 * 40);

    auto stage = [&](const u16* g, int dsec, int nsec) {
        for (int sec = wave; sec < nsec; sec += 8)
            *(s16x8*)(WBUF + (size_t)(dsec + sec) * 512 + lane * 8) =
                *(const s16x8*)(g + (size_t)sec * 512 + lane * 8);
    };

    // ---- A fragments for GEMM1 (2 row-tiles of 16 edges)
    s16x8 aF[2][KA];
    if constexpr (FIRST) {
        for (int s = lane; s < 32 * 32; s += 64) {
            int e = min(ebase + (s >> 5), E_ - 1);    // ghost-edge clamp
            int k = s & 31;
            u16 v = 0;
            if (k < 7)                  v = f2bf(X[(size_t)ei[E_ + e] * 7 + k]);
            else if (k >= 16 && k < 23) v = f2bf(X[(size_t)ei[e] * 7 + (k - 16)]);
            SCw[(s >> 5) * 40 + k] = v;
        }
        #pragma unroll
        for (int rt = 0; rt < 2; ++rt)
            aF[rt][0] = ldv(SCw + (rt * 16 + col) * 40 + kq * 8);  // lgkm-ordered
    } else {
        #pragma unroll
        for (int rt = 0; rt < 2; ++rt) {
            const int e  = min(ebase + rt * 16 + col, E_ - 1);
            const int dn = ei[E_ + e];                // x_i (target)
            const int sn = ei[e];                     // x_j (source)
            #pragma unroll
            for (int s = 0; s < KA; ++s) {
                int b = s * 4 + kq;                   // k-group; k = 8b+j
                int node = (b < 14) ? dn : sn;
                int c = ((b < 14) ? b : b - 14) * 8;
                s16x8 t = {0, 0, 0, 0, 0, 0, 0, 0};
                if (c < 104) t = ldv(H0 + (size_t)node * 104 + c);  // 16B aligned
                aF[rt][s] = t;
            }
        }
    }

    // ---- GEMM1: [32,KP] -> H1 chunks -> persistent a2 fragments
    s16x8 a2[2][10];
    if constexpr (FIRST) {
        stage(W1, 0, 20);                 // whole wt0 (20 KB) fits WBUF
        __syncthreads();
        #pragma unroll 1
        for (int t2 = 0; t2 < 10; ++t2) {
            s16x8 b0 = ldv(WBUF + (t2 * 2) * 512 + fragoff);
            s16x8 b1 = ldv(WBUF + (t2 * 2 + 1) * 512 + fragoff);
            f32x4 z = {0.f, 0.f, 0.f, 0.f};
            f32x4 ac[2][2] = {{z, z}, {z, z}};
            #pragma unroll
            for (int rt = 0; rt < 2; ++rt) {
                ac[rt][0] = MFMA(aF[rt][0], b0, ac[rt][0]);
                ac[rt][1] = MFMA(aF[rt][0], b1, ac[rt][1]);
            }
            const int n = t2 * 32 + col;
            const float bi0 = (n < 300)      ? B1[n]      : 0.f;
            const float bi1 = (n + 16 < 300) ? B1[n + 16] : 0.f;
            #pragma unroll
            for (int rt = 0; rt < 2; ++rt)
                #pragma unroll
                for (int r = 0; r < 4; ++r) {
                    int row = rt * 16 + kq * 4 + r;
                    SCw[row * 40 + col]      = f2bf(fmaxf(ac[rt][0][r] + bi0, 0.f));
                    SCw[row * 40 + col + 16] = f2bf(fmaxf(ac[rt][1][r] + bi1, 0.f));
                }
            #pragma unroll
            for (int rt = 0; rt < 2; ++rt)
                a2[rt][t2] = ldv(SCw + (rt * 16 + col) * 40 + kq * 8);
        }
    } else {
        stage(W1, 0, 14);                 // chunk 0 (14 KB)
        #pragma unroll 1
        for (int t2 = 0; t2 < 10; ++t2) {
            __syncthreads();              // WBUF holds chunk t2
            f32x4 z = {0.f, 0.f, 0.f, 0.f};
            f32x4 ac[2][2] = {{z, z}, {z, z}};
            #pragma unroll
            for (int s = 0; s < KA; ++s) {
                s16x8 b0 = ldv(WBUF + (2 * s) * 512 + fragoff);
                s16x8 b1 = ldv(WBUF + (2 * s + 1) * 512 + fragoff);
                #pragma unroll
                for (int rt = 0; rt < 2; ++rt) {
                    ac[rt][0] = MFMA(aF[rt][s], b0, ac[rt][0]);
                    ac[rt][1] = MFMA(aF[rt][s], b1, ac[rt][1]);
                }
            }
            __syncthreads();              // all waves done reading chunk t2
            if (t2 < 9) stage(W1 + (size_t)(t2 + 1) * 14 * 512, 0, 14);
            const int n = t2 * 32 + col;
            const float bi0 = (n < 300)      ? B1[n]      : 0.f;
            const float bi1 = (n + 16 < 300) ? B1[n + 16] : 0.f;
            #pragma unroll
            for (int rt = 0; rt < 2; ++rt)
                #pragma unroll
                for (int r = 0; r < 4; ++r) {
                    int row = rt * 16 + kq * 4 + r;
                    SCw[row * 40 + col]      = f2bf(fmaxf(ac[rt][0][r] + bi0, 0.f));
                    SCw[row * 40 + col + 16] = f2bf(fmaxf(ac[rt][1][r] + bi1, 0.f));
                }
            #pragma unroll
            for (int rt = 0; rt < 2; ++rt)
                a2[rt][t2] = ldv(SCw + (rt * 16 + col) * 40 + kq * 8);
        }
    }

    f32x4 mac[2][7];
    #pragma unroll
    for (int rt = 0; rt < 2; ++rt)
        #pragma unroll
        for (int u = 0; u < 7; ++u) { f32x4 z = {0.f, 0.f, 0.f, 0.f}; mac[rt][u] = z; }

    // ---- GEMM2 (K=320) fused with GEMM3, 32-wide chunks; staged per chunk
    __syncthreads();                      // phase-1 WBUF reads complete
    stage(W2, 0, 20);
    stage(W3, 20, 7);
    #pragma unroll 1
    for (int ch = 0; ch < 10; ++ch) {
        __syncthreads();                  // WBUF holds chunk ch (W2 + W3)
        f32x4 z = {0.f, 0.f, 0.f, 0.f};
        f32x4 ac[2][2] = {{z, z}, {z, z}};
        #pragma unroll
        for (int s = 0; s < 10; ++s) {
            s16x8 b0 = ldv(WBUF + (2 * s) * 512 + fragoff);
            s16x8 b1 = ldv(WBUF + (2 * s + 1) * 512 + fragoff);
            #pragma unroll
            for (int rt = 0; rt < 2; ++rt) {
                ac[rt][0] = MFMA(a2[rt][s], b0, ac[rt][0]);
                ac[rt][1] = MFMA(a2[rt][s], b1, ac[rt][1]);
            }
        }
        const int n = ch * 32 + col;
        const float bi0 = (n < 300)      ? B2[n]      : 0.f;
        const float bi1 = (n + 16 < 300) ? B2[n + 16] : 0.f;
        #pragma unroll
        for (int rt = 0; rt < 2; ++rt)
            #pragma unroll
            for (int r = 0; r < 4; ++r) {
                int row = rt * 16 + kq * 4 + r;
                SCw[row * 40 + col]      = f2bf(fmaxf(ac[rt][0][r] + bi0, 0.f));
                SCw[row * 40 + col + 16] = f2bf(fmaxf(ac[rt][1][r] + bi1, 0.f));
            }
        s16x8 a3_0 = ldv(SCw + col * 40 + kq * 8);           // wave-private transit
        s16x8 a3_1 = ldv(SCw + (16 + col) * 40 + kq * 8);
        #pragma unroll
        for (int u = 0; u < 7; ++u) {
            s16x8 b3 = ldv(WBUF + (20 + u) * 512 + fragoff);
            mac[0][u] = MFMA(a3_0, b3, mac[0][u]);
            mac[1][u] = MFMA(a3_1, b3, mac[1][u]);
        }
        __syncthreads();                  // all waves done reading chunk ch
        if (ch < 9) {
            stage(W2 + (size_t)(ch + 1) * 20 * 512, 0, 20);
            stage(W3 + (size_t)(ch + 1) * 7 * 512, 20, 7);
        }
    }

    // ---- scatter-max with quad-uniform merge + ghost-edge guards
    #pragma unroll
    for (int rt = 0; rt < 2; ++rt) {
        const int e0 = ebase + rt * 16 + kq * 4;
        int dsts[4];
        #pragma unroll
        for (int r = 0; r < 4; ++r) dsts[r] = ei[E_ + min(e0 + r, E_ - 1)];
        const bool all_valid = (e0 + 3 < E_);
        const bool same = all_valid & (dsts[0] == dsts[1]) & (dsts[0] == dsts[2])
                                    & (dsts[0] == dsts[3]);
        #pragma unroll
        for (int u = 0; u < 7; ++u) {
            int c3 = u * 16 + col;
            if (c3 < 100) {
                float bi = B3[c3];
                if (same) {
                    float m = fmaxf(fmaxf(mac[rt][u][0], mac[rt][u][1]),
                                    fmaxf(mac[rt][u][2], mac[rt][u][3]));
                    float v = fmaxf(m + bi, 0.f);
                    atomicMax((int*)(agg + (size_t)dsts[0] * 100 + c3), __float_as_int(v));
                } else {
                    #pragma unroll
                    for (int r = 0; r < 4; ++r) {
                        if (e0 + r < E_) {
                            float v = fmaxf(mac[rt][u][r] + bi, 0.f);
                            atomicMax((int*)(agg + (size_t)dsts[r] * 100 + c3),
                                      __float_as_int(v));
                        }
                    }
                }
            }
        }
    }
}

// ---------------------------------------------------------------------------
// pool: one block per graph (batch sorted -> binary-search bounds).
// pooled[g] = [addp(100) | meanp(100) | maxp(100) | u(2)]
// ---------------------------------------------------------------------------
__global__ __launch_bounds__(256)
void pool(const float* __restrict__ agg1, const int* __restrict__ batch,
          const float* __restrict__ u, float* __restrict__ pooled)
{
    const int g = blockIdx.x;
    int lo = 0, hi = N_;
    while (lo < hi) { int mid = (lo + hi) >> 1; if (batch[mid] < g) lo = mid + 1; else hi = mid; }
    const int start = lo;
    int lo2 = start, hi2 = N_;
    while (lo2 < hi2) { int mid = (lo2 + hi2) >> 1; if (batch[mid] < g + 1) lo2 = mid + 1; else hi2 = mid; }
    const int end = lo2;

    const int c = threadIdx.x & 127, half = threadIdx.x >> 7;
    float sm = 0.f, mx = 0.f;
    if (c < 100)
        for (int n = start + half; n < end; n += 2) {
            float v = agg1[(size_t)n * 100 + c];
            sm += v; mx = fmaxf(mx, v);
        }
    __shared__ float ssum[128], smax[128];
    if (half) { ssum[c] = sm; smax[c] = mx; }
    __syncthreads();
    if (!half && c < 100) {
        sm += ssum[c]; mx = fmaxf(mx, smax[c]);
        int cnt = end - start;
        pooled[g * 302 + c]       = sm;
        pooled[g * 302 + 100 + c] = sm / fmaxf((float)cnt, 1.f);
        pooled[g * 302 + 200 + c] = mx;   // h>=0 so zero-init max == where(cnt>0,.)
    }
    if (threadIdx.x == 0) {
        pooled[g * 302 + 300] = u[g * 2];
        pooled[g * 302 + 301] = u[g * 2 + 1];
    }
}

// ---------------------------------------------------------------------------
// final 302 -> 100 -> 100 -> 2 MLP, one block per graph, fp32
// ---------------------------------------------------------------------------
__global__ __launch_bounds__(128)
void final_mlp(const float* __restrict__ pooled,
               const float* __restrict__ w1, const float* __restrict__ b1,
               const float* __restrict__ w2, const float* __restrict__ b2,
               const float* __restrict__ w3, const float* __restrict__ b3,
               float* __restrict__ out)
{
    const int g = blockIdx.x, t = threadIdx.x;
    __shared__ float P[302], T1[100], T2[100];
    for (int i = t; i < 302; i += 128) P[i] = pooled[g * 302 + i];
    __syncthreads();
    if (t < 100) {
        float a = b1[t];
        for (int i = 0; i < 302; ++i) a = fmaf(P[i], w1[i * 100 + t], a);
        T1[t] = fmaxf(a, 0.f);
    }
    __syncthreads();
    if (t < 100) {
        float a = b2[t];
        for (int i = 0; i < 100; ++i) a = fmaf(T1[i], w2[i * 100 + t], a);
        T2[t] = fmaxf(a, 0.f);
    }
    __syncthreads();
    if (t < 2) {
        float a = b3[t];
        for (int i = 0; i < 100; ++i) a = fmaf(T2[i], w3[i * 2 + t], a);
        out[g * 2 + t] = a;
    }
}

// ---------------------------------------------------------------------------
extern "C" void kernel_launch(void* const* d_in, const int* in_sizes, int n_in,
                              void* d_out, int out_size, void* d_ws, size_t ws_size,
                              hipStream_t stream)
{
    const float* x     = (const float*)d_in[0];
    const int*   ei    = (const int*)d_in[1];
    const int*   batch = (const int*)d_in[2];
    const float* uu    = (const float*)d_in[3];
    const float *l0w1 = (const float*)d_in[4],  *l0b1 = (const float*)d_in[5];
    const float *l0w2 = (const float*)d_in[6],  *l0b2 = (const float*)d_in[7];
    const float *l0w3 = (const float*)d_in[8],  *l0b3 = (const float*)d_in[9];
    const float *l1w1 = (const float*)d_in[10], *l1b1 = (const float*)d_in[11];
    const float *l1w2 = (const float*)d_in[12], *l1b2 = (const float*)d_in[13];
    const float *l1w3 = (const float*)d_in[14], *l1b3 = (const float*)d_in[15];
    const float *lw1  = (const float*)d_in[16], *lb1  = (const float*)d_in[17];
    const float *lw2  = (const float*)d_in[18], *lb2  = (const float*)d_in[19];
    const float *lw3  = (const float*)d_in[20], *lb3  = (const float*)d_in[21];

    char* w = (char*)d_ws;
    float* agg0   = (float*)(w);                    // 20,000,000 B
    float* agg1   = (float*)(w + 20000000);         // 20,000,000 B
    float* pooled = (float*)(w + 40000000);         //     77,312 B
    u16* wt0    = (u16*)(w + 40077312);             //     20,480 B
    u16* wt1    = (u16*)(w + 40097792);             //    143,360 B
    u16* wt2a   = (u16*)(w + 40241152);             //    204,800 B
    u16* wt2b   = (u16*)(w + 40445952);             //    204,800 B
    u16* wt3a   = (u16*)(w + 40650752);             //     71,680 B
    u16* wt3b   = (u16*)(w + 40722432);             //     71,680 B
    u16* agg0bf = (u16*)(w + 40794112);             // 10,400,000 B (~51.2 MB)

    ModelGNN_35304631174019_kernel<<<11166, 256, 0, stream>>>(
        l0w1, l0w2, l0w3, l1w1, l1w2, l1w3,
        (float4*)d_ws, wt0, wt1, wt2a, wt2b, wt3a, wt3b);
    edge_mlp<true ><<<1563, 512, 0, stream>>>(x, nullptr, ei,
                                              wt0, l0b1, wt2a, l0b2, wt3a, l0b3, agg0);
    convert_bf<<<20313, 256, 0, stream>>>(agg0, agg0bf);
    edge_mlp<false><<<1563, 512, 0, stream>>>(nullptr, agg0bf, ei,
                                              wt1, l1b1, wt2b, l1b2, wt3b, l1b3, agg1);
    pool<<<G_, 256, 0, stream>>>(agg1, batch, uu, pooled);
    final_mlp<<<G_, 128, 0, stream>>>(pooled, lw1, lb1, lw2, lb2, lw3, lb3, (float*)d_out);
}

// Round 16
// 1497.887 us; speedup vs baseline: 1.0114x; 1.0114x over previous
//
#include <hip/hip_runtime.h>

typedef unsigned short u16;
typedef short s16x8 __attribute__((ext_vector_type(8)));   // 8 bf16 bit-patterns
typedef float f32x4 __attribute__((ext_vector_type(4)));

#define DI __device__ __forceinline__

constexpr int N_ = 50000;
constexpr int E_ = 400000;
constexpr int G_ = 64;

DI u16 f2bf(float f) {
    union { unsigned u; float f; } c; c.f = f;
    unsigned u = c.u;
    u += 0x7fffu + ((u >> 16) & 1u);   // RNE
    return (u16)(u >> 16);
}

DI s16x8 ldv(const u16* p) { return *(const s16x8*)p; }
DI f32x4 MFMA(s16x8 a, s16x8 b, f32x4 c) {
    return __builtin_amdgcn_mfma_f32_16x16x32_bf16(a, b, c, 0, 0, 0);
}

// ---------------------------------------------------------------------------
// Named kernel: zero agg0+agg1 (40 MB) + dst-histogram, and repack weights
// f32 -> bf16 in MFMA-fragment-order tiles (lane-order sections, conflict-
// free), folding [xi, xj-xi]@W = xi@(Wa-Wb) + xj@Wb.
// Section = 512 elems = 1 KB; element (col,kq,j) at lane*8+j, lane=kq*16+col.
// W1/W2 sec id = n0c*(2*KA)+s*2+b01 ; W3 sec id = ch*7+u.
// ---------------------------------------------------------------------------
__global__ __launch_bounds__(256)
void ModelGNN_35304631174019_kernel(
          const float* __restrict__ l0w1, const float* __restrict__ l0w2,
          const float* __restrict__ l0w3, const float* __restrict__ l1w1,
          const float* __restrict__ l1w2, const float* __restrict__ l1w3,
          float4* __restrict__ aggz,
          u16* __restrict__ wt0, u16* __restrict__ wt1,
          u16* __restrict__ wt2a, u16* __restrict__ wt2b,
          u16* __restrict__ wt3a, u16* __restrict__ wt3b,
          int* __restrict__ hist)
{
    int i = blockIdx.x * 256 + threadIdx.x;
    if (i < 2500000) { aggz[i] = make_float4(0.f, 0.f, 0.f, 0.f); return; }  // agg0+agg1
    int f = i - 2500000;

    if (f < 10240) {                       // wt0: layer0 W1, KP=32 (KA=1)
        int sec = f >> 9, w = f & 511;
        int lane = w >> 3, j = w & 7;
        int col = lane & 15, kq = lane >> 4;
        int n0c = sec >> 1, b01 = sec & 1;
        int n = n0c * 32 + b01 * 16 + col, k = kq * 8 + j;
        u16 v = 0;
        if (n < 300) {
            if (k < 7) v = f2bf(l0w1[k * 300 + n] - l0w1[(7 + k) * 300 + n]);
            else if (k >= 16 && k < 23) v = f2bf(l0w1[(7 + (k - 16)) * 300 + n]);
        }
        wt0[f] = v; return;
    }
    f -= 10240;
    if (f < 71680) {                       // wt1: layer1 W1, KP=224 (KA=7)
        int sec = f >> 9, w = f & 511;
        int lane = w >> 3, j = w & 7;
        int col = lane & 15, kq = lane >> 4;
        int n0c = sec / 14, r = sec % 14;
        int s = r >> 1, b01 = r & 1;
        int n = n0c * 32 + b01 * 16 + col, k = s * 32 + kq * 8 + j;
        u16 v = 0;
        if (n < 300) {
            if (k < 100) v = f2bf(l1w1[k * 300 + n] - l1w1[(100 + k) * 300 + n]);
            else if (k >= 112 && k < 212) v = f2bf(l1w1[(100 + (k - 112)) * 300 + n]);
        }
        wt1[f] = v; return;
    }
    f -= 71680;
    if (f < 204800) {                      // wt2a / wt2b: 300x300, K=320 (KA=10)
        const float* src = (f < 102400) ? l0w2 : l1w2;
        u16* dst = (f < 102400) ? wt2a : wt2b;
        int f2 = (f < 102400) ? f : f - 102400;
        int sec = f2 >> 9, w = f2 & 511;
        int lane = w >> 3, j = w & 7;
        int col = lane & 15, kq = lane >> 4;
        int n0c = sec / 20, r = sec % 20;
        int s = r >> 1, b01 = r & 1;
        int n = n0c * 32 + b01 * 16 + col, k = s * 32 + kq * 8 + j;
        dst[f2] = (n < 300 && k < 300) ? f2bf(src[k * 300 + n]) : (u16)0;
        return;
    }
    f -= 204800;
    if (f < 71680) {                       // wt3a / wt3b: 300x100 -> [112 n3][320 k]
        const float* src = (f < 35840) ? l0w3 : l1w3;
        u16* dst = (f < 35840) ? wt3a : wt3b;
        int f2 = (f < 35840) ? f : f - 35840;
        int sec = f2 >> 9, w = f2 & 511;
        int lane = w >> 3, j = w & 7;
        int col = lane & 15, kq = lane >> 4;
        int ch = sec / 7, u = sec % 7;
        int n3 = u * 16 + col, k = ch * 32 + kq * 8 + j;
        dst[f2] = (n3 < 100 && k < 300) ? f2bf(src[k * 100 + n3]) : (u16)0;
        return;
    }
    f -= 71680;
    if (f < N_) hist[f] = 0;               // zero dst-histogram
}

// ---------------------------------------------------------------------------
// counting sort of edges by dst. Bin-internal order nondeterministic
// (atomicAdd) — harmless: segment-max is order-independent.
// ---------------------------------------------------------------------------
__global__ __launch_bounds__(256)
void hist_k(const int* __restrict__ ei, int* __restrict__ hist)
{
    int e = blockIdx.x * 256 + threadIdx.x;
    if (e < E_) atomicAdd(&hist[ei[E_ + e]], 1);
}

__global__ __launch_bounds__(1024)
void scan_k(int* __restrict__ hist)     // in-place: hist -> exclusive offsets
{
    __shared__ int part[1024];
    const int t = threadIdx.x;
    const int base = t * 49, end = min(base + 49, N_);
    int s = 0;
    for (int i = base; i < end; ++i) s += hist[i];
    part[t] = s;
    __syncthreads();
    for (int d = 1; d < 1024; d <<= 1) {
        int v = (t >= d) ? part[t - d] : 0;
        __syncthreads();
        if (t >= d) part[t] += v;
        __syncthreads();
    }
    int run = part[t] - s;                 // exclusive prefix of this range
    for (int i = base; i < end; ++i) { int c = hist[i]; hist[i] = run; run += c; }
}

__global__ __launch_bounds__(256)
void scatter_k(const int* __restrict__ ei, int* __restrict__ off,
               int* __restrict__ esrc, int* __restrict__ edst)
{
    int e = blockIdx.x * 256 + threadIdx.x;
    if (e < E_) {
        int d = ei[E_ + e], s = ei[e];
        int p = atomicAdd(&off[d], 1);
        edst[p] = d; esrc[p] = s;
    }
}

// ---------------------------------------------------------------------------
// convert: agg0 f32[50000][100] -> agg0bf bf16[50000][104] (4 zero pad cols).
// Same RNE rounding point as before -> bit-identical math downstream.
// ---------------------------------------------------------------------------
__global__ __launch_bounds__(256)
void convert_bf(const float* __restrict__ agg0, u16* __restrict__ out)
{
    int i = blockIdx.x * 256 + threadIdx.x;
    if (i >= N_ * 104) return;
    int n = i / 104, c = i - n * 104;
    out[i] = (c < 100) ? f2bf(agg0[n * 100 + c]) : (u16)0;
}

// ---------------------------------------------------------------------------
// edge_mlp: fused per-edge 3-layer MLP + clamped scatter-max via MFMA.
// R16: edges DST-SORTED; scatter uses a segmented suffix-max per quad (one
// atomic per dst-run instead of 4: R15 evidence shows the 2.5M scattered
// atomics dominate FETCH/WRITE — 450MB WRITE invariant across R11-R15, FETCH
// > staging stream). Block index XCD-swizzled: ebi=(bid&7)*196+bid/8 keeps a
// node's whole atomic fan-in on one XCD L2 (no line migration). Geometry and
// conflict-free block-shared weight staging unchanged from R15 (512 thr,
// 32 edges/wave, 256 edges/block).
// Layouts (m89/m120): A: m=lane&15,k=quad*8+j ; B: n=lane&15,k=quad*8+j ;
// C/D: col=lane&15, row=quad*4+reg.
// relu(where(cnt>0,segmax,0)) == int atomicMax of relu'd msgs into 0-init buf;
// max_r(relu(m_r+b)) == relu(max_r(m_r)+b) (relu monotone, b uniform).
// Ghost edges (grid overshoot) are clamped to E_-1: duplicate message to the
// same dst — absorbed exactly by max.
// ---------------------------------------------------------------------------
template<bool FIRST>
__global__ __launch_bounds__(512, 2)
void edge_mlp(const float* __restrict__ X, const u16* __restrict__ H0,
              const int* __restrict__ esrc, const int* __restrict__ edst,
              const u16* __restrict__ W1, const float* __restrict__ B1,
              const u16* __restrict__ W2, const float* __restrict__ B2,
              const u16* __restrict__ W3, const float* __restrict__ B3,
              float* __restrict__ agg)
{
    constexpr int KP = FIRST ? 32 : 224;
    constexpr int KA = KP / 32;                       // 1 or 7
    __shared__ __align__(16) u16 WBUF[27 * 512];      // 27,648 B block-shared
    __shared__ __align__(16) u16 SCR[8 * 32 * 40];    // 20,480 B wave-private slices

    const int tid  = threadIdx.x;
    const int wave = tid >> 6, lane = tid & 63;
    const int col  = lane & 15, kq = lane >> 4;
    const int ebi  = (blockIdx.x & 7) * 196 + (blockIdx.x >> 3);   // XCD swizzle
    const int ebase = ebi * 256 + wave * 32;          // 32 edges per wave
    const int fragoff = lane * 8;                     // lane-order: conflict-free
    u16* SCw = SCR + wave * (32 * 40);

    auto stage = [&](const u16* g, int dsec, int nsec) {
        for (int sec = wave; sec < nsec; sec += 8)
            *(s16x8*)(WBUF + (size_t)(dsec + sec) * 512 + lane * 8) =
                *(const s16x8*)(g + (size_t)sec * 512 + lane * 8);
    };

    // ---- A fragments for GEMM1 (2 row-tiles of 16 edges)
    s16x8 aF[2][KA];
    if constexpr (FIRST) {
        for (int s = lane; s < 32 * 32; s += 64) {
            int e = min(ebase + (s >> 5), E_ - 1);    // ghost-edge clamp
            int k = s & 31;
            u16 v = 0;
            if (k < 7)                  v = f2bf(X[(size_t)edst[e] * 7 + k]);
            else if (k >= 16 && k < 23) v = f2bf(X[(size_t)esrc[e] * 7 + (k - 16)]);
            SCw[(s >> 5) * 40 + k] = v;
        }
        #pragma unroll
        for (int rt = 0; rt < 2; ++rt)
            aF[rt][0] = ldv(SCw + (rt * 16 + col) * 40 + kq * 8);  // lgkm-ordered
    } else {
        #pragma unroll
        for (int rt = 0; rt < 2; ++rt) {
            const int e  = min(ebase + rt * 16 + col, E_ - 1);
            const int dn = edst[e];                   // x_i (target) — run-sequential
            const int sn = esrc[e];                   // x_j (source)
            #pragma unroll
            for (int s = 0; s < KA; ++s) {
                int b = s * 4 + kq;                   // k-group; k = 8b+j
                int node = (b < 14) ? dn : sn;
                int c = ((b < 14) ? b : b - 14) * 8;
                s16x8 t = {0, 0, 0, 0, 0, 0, 0, 0};
                if (c < 104) t = ldv(H0 + (size_t)node * 104 + c);  // 16B aligned
                aF[rt][s] = t;
            }
        }
    }

    // ---- GEMM1: [32,KP] -> H1 chunks -> persistent a2 fragments
    s16x8 a2[2][10];
    if constexpr (FIRST) {
        stage(W1, 0, 20);                 // whole wt0 (20 KB) fits WBUF
        __syncthreads();
        #pragma unroll 1
        for (int t2 = 0; t2 < 10; ++t2) {
            s16x8 b0 = ldv(WBUF + (t2 * 2) * 512 + fragoff);
            s16x8 b1 = ldv(WBUF + (t2 * 2 + 1) * 512 + fragoff);
            f32x4 z = {0.f, 0.f, 0.f, 0.f};
            f32x4 ac[2][2] = {{z, z}, {z, z}};
            #pragma unroll
            for (int rt = 0; rt < 2; ++rt) {
                ac[rt][0] = MFMA(aF[rt][0], b0, ac[rt][0]);
                ac[rt][1] = MFMA(aF[rt][0], b1, ac[rt][1]);
            }
            const int n = t2 * 32 + col;
            const float bi0 = (n < 300)      ? B1[n]      : 0.f;
            const float bi1 = (n + 16 < 300) ? B1[n + 16] : 0.f;
            #pragma unroll
            for (int rt = 0; rt < 2; ++rt)
                #pragma unroll
                for (int r = 0; r < 4; ++r) {
                    int row = rt * 16 + kq * 4 + r;
                    SCw[row * 40 + col]      = f2bf(fmaxf(ac[rt][0][r] + bi0, 0.f));
                    SCw[row * 40 + col + 16] = f2bf(fmaxf(ac[rt][1][r] + bi1, 0.f));
                }
            #pragma unroll
            for (int rt = 0; rt < 2; ++rt)
                a2[rt][t2] = ldv(SCw + (rt * 16 + col) * 40 + kq * 8);
        }
    } else {
        stage(W1, 0, 14);                 // chunk 0 (14 KB)
        #pragma unroll 1
        for (int t2 = 0; t2 < 10; ++t2) {
            __syncthreads();              // WBUF holds chunk t2
            f32x4 z = {0.f, 0.f, 0.f, 0.f};
            f32x4 ac[2][2] = {{z, z}, {z, z}};
            #pragma unroll
            for (int s = 0; s < KA; ++s) {
                s16x8 b0 = ldv(WBUF + (2 * s) * 512 + fragoff);
                s16x8 b1 = ldv(WBUF + (2 * s + 1) * 512 + fragoff);
                #pragma unroll
                for (int rt = 0; rt < 2; ++rt) {
                    ac[rt][0] = MFMA(aF[rt][s], b0, ac[rt][0]);
                    ac[rt][1] = MFMA(aF[rt][s], b1, ac[rt][1]);
                }
            }
            __syncthreads();              // all waves done reading chunk t2
            if (t2 < 9) stage(W1 + (size_t)(t2 + 1) * 14 * 512, 0, 14);
            const int n = t2 * 32 + col;
            const float bi0 = (n < 300)      ? B1[n]      : 0.f;
            const float bi1 = (n + 16 < 300) ? B1[n + 16] : 0.f;
            #pragma unroll
            for (int rt = 0; rt < 2; ++rt)
                #pragma unroll
                for (int r = 0; r < 4; ++r) {
                    int row = rt * 16 + kq * 4 + r;
                    SCw[row * 40 + col]      = f2bf(fmaxf(ac[rt][0][r] + bi0, 0.f));
                    SCw[row * 40 + col + 16] = f2bf(fmaxf(ac[rt][1][r] + bi1, 0.f));
                }
            #pragma unroll
            for (int rt = 0; rt < 2; ++rt)
                a2[rt][t2] = ldv(SCw + (rt * 16 + col) * 40 + kq * 8);
        }
    }

    f32x4 mac[2][7];
    #pragma unroll
    for (int rt = 0; rt < 2; ++rt)
        #pragma unroll
        for (int u = 0; u < 7; ++u) { f32x4 z = {0.f, 0.f, 0.f, 0.f}; mac[rt][u] = z; }

    // ---- GEMM2 (K=320) fused with GEMM3, 32-wide chunks; staged per chunk
    __syncthreads();                      // phase-1 WBUF reads complete
    stage(W2, 0, 20);
    stage(W3, 20, 7);
    #pragma unroll 1
    for (int ch = 0; ch < 10; ++ch) {
        __syncthreads();                  // WBUF holds chunk ch (W2 + W3)
        f32x4 z = {0.f, 0.f, 0.f, 0.f};
        f32x4 ac[2][2] = {{z, z}, {z, z}};
        #pragma unroll
        for (int s = 0; s < 10; ++s) {
            s16x8 b0 = ldv(WBUF + (2 * s) * 512 + fragoff);
            s16x8 b1 = ldv(WBUF + (2 * s + 1) * 512 + fragoff);
            #pragma unroll
            for (int rt = 0; rt < 2; ++rt) {
                ac[rt][0] = MFMA(a2[rt][s], b0, ac[rt][0]);
                ac[rt][1] = MFMA(a2[rt][s], b1, ac[rt][1]);
            }
        }
        const int n = ch * 32 + col;
        const float bi0 = (n < 300)      ? B2[n]      : 0.f;
        const float bi1 = (n + 16 < 300) ? B2[n + 16] : 0.f;
        #pragma unroll
        for (int rt = 0; rt < 2; ++rt)
            #pragma unroll
            for (int r = 0; r < 4; ++r) {
                int row = rt * 16 + kq * 4 + r;
                SCw[row * 40 + col]      = f2bf(fmaxf(ac[rt][0][r] + bi0, 0.f));
                SCw[row * 40 + col + 16] = f2bf(fmaxf(ac[rt][1][r] + bi1, 0.f));
            }
        s16x8 a3_0 = ldv(SCw + col * 40 + kq * 8);           // wave-private transit
        s16x8 a3_1 = ldv(SCw + (16 + col) * 40 + kq * 8);
        #pragma unroll
        for (int u = 0; u < 7; ++u) {
            s16x8 b3 = ldv(WBUF + (20 + u) * 512 + fragoff);
            mac[0][u] = MFMA(a3_0, b3, mac[0][u]);
            mac[1][u] = MFMA(a3_1, b3, mac[1][u]);
        }
        __syncthreads();                  // all waves done reading chunk ch
        if (ch < 9) {
            stage(W2 + (size_t)(ch + 1) * 20 * 512, 0, 20);
            stage(W3 + (size_t)(ch + 1) * 7 * 512, 20, 7);
        }
    }

    // ---- scatter-max: segmented suffix-max per quad of sorted edges.
    // One atomic per dst-run (exp ~1.375/quad at avg degree 8 vs 4 before).
    #pragma unroll
    for (int rt = 0; rt < 2; ++rt) {
        const int e0 = ebase + rt * 16 + kq * 4;
        const int d0 = edst[min(e0 + 0, E_ - 1)];
        const int d1 = edst[min(e0 + 1, E_ - 1)];
        const int d2 = edst[min(e0 + 2, E_ - 1)];
        const int d3 = edst[min(e0 + 3, E_ - 1)];
        const bool m1 = (d1 == d0), m2 = (d2 == d1), m3 = (d3 == d2);
        #pragma unroll
        for (int u = 0; u < 7; ++u) {
            int c3 = u * 16 + col;
            if (c3 < 100) {
                const float bi = B3[c3];
                const float v0 = mac[rt][u][0], v1 = mac[rt][u][1];
                const float v2 = mac[rt][u][2], v3 = mac[rt][u][3];
                const float s3v = v3;
                const float s2v = m3 ? fmaxf(v2, s3v) : v2;
                const float s1v = m2 ? fmaxf(v1, s2v) : v1;
                const float s0v = m1 ? fmaxf(v0, s1v) : v0;
                atomicMax((int*)(agg + (size_t)d0 * 100 + c3),
                          __float_as_int(fmaxf(s0v + bi, 0.f)));
                if (!m1) atomicMax((int*)(agg + (size_t)d1 * 100 + c3),
                                   __float_as_int(fmaxf(s1v + bi, 0.f)));
                if (!m2) atomicMax((int*)(agg + (size_t)d2 * 100 + c3),
                                   __float_as_int(fmaxf(s2v + bi, 0.f)));
                if (!m3) atomicMax((int*)(agg + (size_t)d3 * 100 + c3),
                                   __float_as_int(fmaxf(s3v + bi, 0.f)));
            }
        }
    }
}

// ---------------------------------------------------------------------------
// pool: one block per graph (batch sorted -> binary-search bounds).
// pooled[g] = [addp(100) | meanp(100) | maxp(100) | u(2)]
// ---------------------------------------------------------------------------
__global__ __launch_bounds__(256)
void pool(const float* __restrict__ agg1, const int* __restrict__ batch,
          const float* __restrict__ u, float* __restrict__ pooled)
{
    const int g = blockIdx.x;
    int lo = 0, hi = N_;
    while (lo < hi) { int mid = (lo + hi) >> 1; if (batch[mid] < g) lo = mid + 1; else hi = mid; }
    const int start = lo;
    int lo2 = start, hi2 = N_;
    while (lo2 < hi2) { int mid = (lo2 + hi2) >> 1; if (batch[mid] < g + 1) lo2 = mid + 1; else hi2 = mid; }
    const int end = lo2;

    const int c = threadIdx.x & 127, half = threadIdx.x >> 7;
    float sm = 0.f, mx = 0.f;
    if (c < 100)
        for (int n = start + half; n < end; n += 2) {
            float v = agg1[(size_t)n * 100 + c];
            sm += v; mx = fmaxf(mx, v);
        }
    __shared__ float ssum[128], smax[128];
    if (half) { ssum[c] = sm; smax[c] = mx; }
    __syncthreads();
    if (!half && c < 100) {
        sm += ssum[c]; mx = fmaxf(mx, smax[c]);
        int cnt = end - start;
        pooled[g * 302 + c]       = sm;
        pooled[g * 302 + 100 + c] = sm / fmaxf((float)cnt, 1.f);
        pooled[g * 302 + 200 + c] = mx;   // h>=0 so zero-init max == where(cnt>0,.)
    }
    if (threadIdx.x == 0) {
        pooled[g * 302 + 300] = u[g * 2];
        pooled[g * 302 + 301] = u[g * 2 + 1];
    }
}

// ---------------------------------------------------------------------------
// final 302 -> 100 -> 100 -> 2 MLP, one block per graph, fp32
// ---------------------------------------------------------------------------
__global__ __launch_bounds__(128)
void final_mlp(const float* __restrict__ pooled,
               const float* __restrict__ w1, const float* __restrict__ b1,
               const float* __restrict__ w2, const float* __restrict__ b2,
               const float* __restrict__ w3, const float* __restrict__ b3,
               float* __restrict__ out)
{
    const int g = blockIdx.x, t = threadIdx.x;
    __shared__ float P[302], T1[100], T2[100];
    for (int i = t; i < 302; i += 128) P[i] = pooled[g * 302 + i];
    __syncthreads();
    if (t < 100) {
        float a = b1[t];
        for (int i = 0; i < 302; ++i) a = fmaf(P[i], w1[i * 100 + t], a);
        T1[t] = fmaxf(a, 0.f);
    }
    __syncthreads();
    if (t < 100) {
        float a = b2[t];
        for (int i = 0; i < 100; ++i) a = fmaf(T1[i], w2[i * 100 + t], a);
        T2[t] = fmaxf(a, 0.f);
    }
    __syncthreads();
    if (t < 2) {
        float a = b3[t];
        for (int i = 0; i < 100; ++i) a = fmaf(T2[i], w3[i * 2 + t], a);
        out[g * 2 + t] = a;
    }
}

// ---------------------------------------------------------------------------
extern "C" void kernel_launch(void* const* d_in, const int* in_sizes, int n_in,
                              void* d_out, int out_size, void* d_ws, size_t ws_size,
                              hipStream_t stream)
{
    const float* x     = (const float*)d_in[0];
    const int*   ei    = (const int*)d_in[1];
    const int*   batch = (const int*)d_in[2];
    const float* uu    = (const float*)d_in[3];
    const float *l0w1 = (const float*)d_in[4],  *l0b1 = (const float*)d_in[5];
    const float *l0w2 = (const float*)d_in[6],  *l0b2 = (const float*)d_in[7];
    const float *l0w3 = (const float*)d_in[8],  *l0b3 = (const float*)d_in[9];
    const float *l1w1 = (const float*)d_in[10], *l1b1 = (const float*)d_in[11];
    const float *l1w2 = (const float*)d_in[12], *l1b2 = (const float*)d_in[13];
    const float *l1w3 = (const float*)d_in[14], *l1b3 = (const float*)d_in[15];
    const float *lw1  = (const float*)d_in[16], *lb1  = (const float*)d_in[17];
    const float *lw2  = (const float*)d_in[18], *lb2  = (const float*)d_in[19];
    const float *lw3  = (const float*)d_in[20], *lb3  = (const float*)d_in[21];

    char* w = (char*)d_ws;
    float* agg0   = (float*)(w);                    // 20,000,000 B
    float* agg1   = (float*)(w + 20000000);         // 20,000,000 B
    float* pooled = (float*)(w + 40000000);         //     77,312 B
    u16* wt0    = (u16*)(w + 40077312);             //     20,480 B
    u16* wt1    = (u16*)(w + 40097792);             //    143,360 B
    u16* wt2a   = (u16*)(w + 40241152);             //    204,800 B
    u16* wt2b   = (u16*)(w + 40445952);             //    204,800 B
    u16* wt3a   = (u16*)(w + 40650752);             //     71,680 B
    u16* wt3b   = (u16*)(w + 40722432);             //     71,680 B
    u16* agg0bf = (u16*)(w + 40794112);             // 10,400,000 B
    int* hist   = (int*)(w + 51194112);             //    200,000 B
    int* esrc   = (int*)(w + 51394112);             //  1,600,000 B
    int* edst   = (int*)(w + 52994112);             //  1,600,000 B (~54.6 MB)

    ModelGNN_35304631174019_kernel<<<11362, 256, 0, stream>>>(
        l0w1, l0w2, l0w3, l1w1, l1w2, l1w3,
        (float4*)d_ws, wt0, wt1, wt2a, wt2b, wt3a, wt3b, hist);
    hist_k<<<1563, 256, 0, stream>>>(ei, hist);
    scan_k<<<1, 1024, 0, stream>>>(hist);
    scatter_k<<<1563, 256, 0, stream>>>(ei, hist, esrc, edst);
    edge_mlp<true ><<<1568, 512, 0, stream>>>(x, nullptr, esrc, edst,
                                              wt0, l0b1, wt2a, l0b2, wt3a, l0b3, agg0);
    convert_bf<<<20313, 256, 0, stream>>>(agg0, agg0bf);
    edge_mlp<false><<<1568, 512, 0, stream>>>(nullptr, agg0bf, esrc, edst,
                                              wt1, l1b1, wt2b, l1b2, wt3b, l1b3, agg1);
    pool<<<G_, 256, 0, stream>>>(agg1, batch, uu, pooled);
    final_mlp<<<G_, 128, 0, stream>>>(pooled, lw1, lb1, lw2, lb2, lw3, lb3, (float*)d_out);
}